// Round 5
// baseline (113.658 us; speedup 1.0000x reference)
//
#include <hip/hip_runtime.h>

#define NN 768
#define NPAIRS ((NN * (NN - 1)) / 2)   // 294528
#define MARGIN_F 0.01f

__global__ void gg_zero(float* out) { *out = 0.0f; }

__global__ __launch_bounds__(256) void gg_main(const float* __restrict__ pos,
                                               float* __restrict__ out,
                                               float inv_total) {
    int p = blockIdx.x * blockDim.x + threadIdx.x;
    float acc = 0.0f;

    if (p < NPAIRS) {
        // ---- unrank linear pair index p -> (i, j), i < j ----
        // off(i) = i*(2N-1-i)/2 ; want largest i with off(i) <= p
        const float A = 2.0f * NN - 1.0f;          // 1535
        float disc = A * A - 8.0f * (float)p;      // all integers < 2^24, exact in f32
        int i = (int)((A - __builtin_amdgcn_sqrtf(disc)) * 0.5f);
        if (i < 0) i = 0;
        if (i > NN - 2) i = NN - 2;
        // integer fixup (sqrt rounding can be off by 1)
        while (((i + 1) * (2 * NN - 1 - (i + 1))) / 2 <= p) ++i;
        while ((i * (2 * NN - 1 - i)) / 2 > p) --i;
        int off = (i * (2 * NN - 1 - i)) / 2;
        int j = i + 1 + (p - off);

        // ---- per-pair precompute: midpoint + radius ----
        float xix = pos[2 * i], xiy = pos[2 * i + 1];
        float xjx = pos[2 * j], xjy = pos[2 * j + 1];
        float mx = 0.5f * (xix + xjx);
        float my = 0.5f * (xiy + xjy);
        float ddx = xix - xjx, ddy = xiy - xjy;
        float r = 0.5f * __builtin_amdgcn_sqrtf(fmaf(ddx, ddx, ddy * ddy)) + MARGIN_F;

        // ---- inner loop over all nodes (wave-uniform loads -> s_load) ----
        #pragma unroll 8
        for (int k = 0; k < NN; ++k) {
            float dx = pos[2 * k]     - mx;
            float dy = pos[2 * k + 1] - my;
            float d2 = fmaf(dx, dx, dy * dy);
            float d  = __builtin_amdgcn_sqrtf(d2);
            float t  = fmaxf(r - d, 0.0f);
            acc = fmaf(t, t, acc);
        }
    }

    // ---- wave reduce (64 lanes) ----
    for (int o = 32; o > 0; o >>= 1) acc += __shfl_down(acc, o);

    __shared__ float ws[4];   // 256 threads / 64
    int lane = threadIdx.x & 63;
    int wid  = threadIdx.x >> 6;
    if (lane == 0) ws[wid] = acc;
    __syncthreads();
    if (threadIdx.x == 0) {
        float s = (ws[0] + ws[1]) + (ws[2] + ws[3]);
        atomicAdd(out, s * inv_total);
    }
}

extern "C" void kernel_launch(void* const* d_in, const int* in_sizes, int n_in,
                              void* d_out, int out_size, void* d_ws, size_t ws_size,
                              hipStream_t stream) {
    const float* pos = (const float*)d_in[0];
    float* out = (float*)d_out;

    // d_out is re-poisoned to 0xAA before every launch -> must zero it ourselves
    gg_zero<<<1, 1, 0, stream>>>(out);

    double total = (double)NN * (double)NPAIRS;   // 768 * 294528
    float inv_total = (float)(1.0 / total);

    int blocks = (NPAIRS + 255) / 256;            // 1151
    gg_main<<<blocks, 256, 0, stream>>>(pos, out, inv_total);
}

// Round 6
// 111.066 us; speedup vs baseline: 1.0233x; 1.0233x over previous
//
#include <hip/hip_runtime.h>

#define NN 768
#define NPAIRS ((NN * (NN - 1)) / 2)   // 294528
#define MARGIN_F 0.01f
#define CHUNK 256                      // k-nodes per thread (768/3)
#define NCHUNK 3

// Pre-pass: pack per-node (x, y, x^2+y^2, 0) into d_ws for scalar dwordx4 loads.
__global__ __launch_bounds__(256) void gg_pre(const float* __restrict__ pos,
                                              float4* __restrict__ nd) {
    int i = blockIdx.x * blockDim.x + threadIdx.x;
    if (i < NN) {
        float x = pos[2 * i], y = pos[2 * i + 1];
        nd[i] = make_float4(x, y, fmaf(x, x, y * y), 0.0f);
    }
}

__global__ __launch_bounds__(256) void gg_main(const float* __restrict__ pos,
                                               const float4* __restrict__ nd,
                                               float* __restrict__ out,
                                               float inv_total) {
    int p = blockIdx.x * blockDim.x + threadIdx.x;
    int kbase = blockIdx.y * CHUNK;
    float acc = 0.0f;

    if (p < NPAIRS) {
        // ---- unrank linear pair index p -> (i, j), i < j ----
        const float A = 2.0f * NN - 1.0f;          // 1535
        float disc = A * A - 8.0f * (float)p;      // integers < 2^24, exact in f32
        int i = (int)((A - __builtin_amdgcn_sqrtf(disc)) * 0.5f);
        if (i < 0) i = 0;
        if (i > NN - 2) i = NN - 2;
        while (((i + 1) * (2 * NN - 1 - (i + 1))) / 2 <= p) ++i;
        while ((i * (2 * NN - 1 - i)) / 2 > p) --i;
        int off = (i * (2 * NN - 1 - i)) / 2;
        int j = i + 1 + (p - off);

        // ---- per-pair: midpoint, radius, quadratic-form constants ----
        float xix = pos[2 * i], xiy = pos[2 * i + 1];
        float xjx = pos[2 * j], xjy = pos[2 * j + 1];
        float mx = 0.5f * (xix + xjx);
        float my = 0.5f * (xiy + xjy);
        float ddx = xix - xjx, ddy = xiy - xjy;
        float r  = 0.5f * __builtin_amdgcn_sqrtf(fmaf(ddx, ddx, ddy * ddy)) + MARGIN_F;
        float cx = -2.0f * mx;
        float cy = -2.0f * my;
        float cc = fmaf(mx, mx, my * my);          // |mid|^2

        // ---- inner loop: dist^2 = |x_k|^2 - 2 x_k . mid + |mid|^2 ----
        // nd[k] is wave-uniform -> scalar s_load path; 6 VALU + 1 sqrt per term
        #pragma unroll 8
        for (int k = kbase; k < kbase + CHUNK; ++k) {
            float4 n = nd[k];
            float c  = cc + n.z;
            float d2 = fmaf(n.x, cx, fmaf(n.y, cy, c));
            float d  = __builtin_amdgcn_sqrtf(d2);
            float t  = fmaxf(r - d, 0.0f);
            acc = fmaf(t, t, acc);
        }
    }

    // ---- wave reduce (64 lanes) ----
    for (int o = 32; o > 0; o >>= 1) acc += __shfl_down(acc, o);

    __shared__ float ws[4];
    int lane = threadIdx.x & 63;
    int wid  = threadIdx.x >> 6;
    if (lane == 0) ws[wid] = acc;
    __syncthreads();
    if (threadIdx.x == 0) {
        float s = (ws[0] + ws[1]) + (ws[2] + ws[3]);
        atomicAdd(out, s * inv_total);
    }
}

extern "C" void kernel_launch(void* const* d_in, const int* in_sizes, int n_in,
                              void* d_out, int out_size, void* d_ws, size_t ws_size,
                              hipStream_t stream) {
    const float* pos = (const float*)d_in[0];
    float* out = (float*)d_out;
    float4* nd = (float4*)d_ws;

    // d_out / d_ws are re-poisoned 0xAA before every launch
    hipMemsetAsync(out, 0, sizeof(float), stream);   // graph-capture-legal memset node
    gg_pre<<<NCHUNK, 256, 0, stream>>>(pos, nd);

    double total = (double)NN * (double)NPAIRS;
    float inv_total = (float)(1.0 / total);

    dim3 grid((NPAIRS + 255) / 256, NCHUNK);         // 1151 x 3 blocks
    gg_main<<<grid, 256, 0, stream>>>(pos, nd, out, inv_total);
}